// Round 8
// baseline (168.482 us; speedup 1.0000x reference)
//
#include <hip/hip_runtime.h>
#include <cstdint>

// BasisFunction1D: out[o,b] = sum_i (1-d)*P[idx,o,i] + d*P[idx+1,o,i]
//
// R7 = R6 structure at 512 thr/block, 2 blocks/CU for cross-block overlap.
//   Q2[s][i][g][ow]: per-(s,i) slab = 128 g x 16 B = 2 KB contiguous.
//   T[i][b] = (idx*16) | (f16(d) << 16)   -- low16 is a ready byte offset.
//   main: 512 thr = 8 waves = 512 b x 4 o per block, grid 512 (2/CU).
//     16 fully-unrolled phases of 8 i, double-buffered 32 KB LDS.
//     Reg staging: 2x dwordx4 (phase p+1) loaded at top of phase p,
//     2x ds_write_b128 before the single per-phase barrier. T prefetched
//     one phase ahead. Inner iter: v_and + v_and_or + ds_read_b128 + 4 fdot2.

#define NG 128
#define NI 128
#define NO 128
#define NB 8192
#define WO 4
#define PH 8
#define NPH (NI / PH)
#define BT 512                      // threads per main block
#define PHW (PH * NG * WO)          // u32 per phase slab region (4096)

using half2v = __attribute__((ext_vector_type(2))) _Float16;

__device__ inline uint32_t pack_f16x2(float lo, float hi) {
    _Float16 hl = (_Float16)lo, hh = (_Float16)hi;
    return (uint32_t)__builtin_bit_cast(unsigned short, hl) |
           ((uint32_t)__builtin_bit_cast(unsigned short, hh) << 16);
}

// ---- K1: P[g,o,i] -> Q2[((s*NI+i)*NG+g)*4+ow] = pack(P, dP), o=s*4+ow ----
__global__ __launch_bounds__(256) void build_q(const float* __restrict__ P,
                                               uint32_t* __restrict__ Q2) {
    __shared__ float lp[32][129];
    __shared__ float ln[32][129];
    const int g  = blockIdx.x >> 2;
    const int o0 = (blockIdx.x & 3) * 32;
    const int t  = threadIdx.x;
    #pragma unroll
    for (int p = 0; p < 16; ++p) {
        int e = p * 256 + t;
        int ol = e >> 7, i = e & 127;
        lp[ol][i] = P[(size_t)(g * NO + o0 + ol) * NI + i];
        ln[ol][i] = P[(size_t)((g + 1) * NO + o0 + ol) * NI + i];
    }
    __syncthreads();
    #pragma unroll
    for (int p = 0; p < 4; ++p) {
        int e = p * 256 + t;          // 8 s_loc x 128 i
        int sl = e >> 7, i = e & 127;
        uint32_t r[4];
        #pragma unroll
        for (int ow = 0; ow < 4; ++ow) {
            float pl = lp[sl * 4 + ow][i];
            float dd = ln[sl * 4 + ow][i] - pl;
            r[ow] = pack_f16x2(pl, dd);
        }
        int s = (o0 >> 2) + sl;
        *(uint4*)(Q2 + ((size_t)(s * NI + i) * NG + g) * 4) =
            make_uint4(r[0], r[1], r[2], r[3]);
    }
}

// ---- K2: bucketize x -> T[i][b] = (idx*16) | (f16(d) << 16) ----
__global__ __launch_bounds__(256) void build_t(const float* __restrict__ x,
                                               const float* __restrict__ borders,
                                               const float* __restrict__ icl,
                                               uint32_t* __restrict__ T) {
    const int e0 = (blockIdx.x * 256 + threadIdx.x) * 4;
    const float4 xv = *(const float4*)(x + e0);
    uint32_t r[4];
    const float xs[4] = {xv.x, xv.y, xv.z, xv.w};
    #pragma unroll
    for (int k = 0; k < 4; ++k) {
        float v = xs[k];
        float ea = __expf(-fabsf(v));
        float cdf = v > 0.f ? 1.f - 0.5f * ea : 0.5f * ea;
        int idx = (int)(cdf * 128.f);
        idx = idx > 127 ? 127 : idx;
        float d = (v - borders[idx]) * icl[idx];
        _Float16 hd = (_Float16)d;
        r[k] = ((uint32_t)idx << 4) |
               ((uint32_t)__builtin_bit_cast(unsigned short, hd) << 16);
    }
    *(uint4*)(T + e0) = make_uint4(r[0], r[1], r[2], r[3]);
}

// ---- K3: main. 512 thr; 512 b x 4 o; reg-staged double-buffered slabs ----
__global__ __launch_bounds__(512) void main_k(const uint32_t* __restrict__ Q2,
                                              const uint32_t* __restrict__ T,
                                              float* __restrict__ out) {
    __shared__ uint32_t slab[2][PH][NG * WO];   // 32 KB
    const int t    = threadIdx.x;
    const int bx   = blockIdx.x;
    const int s    = bx & 31;                   // o-slice (4 o)
    const int bblk = (bx >> 5) * BT;            // b-tile of 512
    const int bme  = bblk + t;                  // lane's batch
    const uint32_t* Qs = Q2 + (size_t)s * NI * NG * WO;

    float a0 = 0.f, a1 = 0.f, a2 = 0.f, a3 = 0.f;

    // prologue: stage phase 0 (2 uint4 per lane) + T phase 0
    uint32_t treg[PH];
    {
        uint4 q0 = *(const uint4*)(Qs + (size_t)t * 4);
        uint4 q1 = *(const uint4*)(Qs + (size_t)(t + BT) * 4);
        #pragma unroll
        for (int il = 0; il < PH; ++il)
            treg[il] = T[(size_t)il * NB + bme];
        ((uint4*)&slab[0][0][0])[t]      = q0;
        ((uint4*)&slab[0][0][0])[t + BT] = q1;
    }
    __syncthreads();

    #pragma unroll
    for (int p = 0; p < NPH; ++p) {
        const int cur = p & 1;
        uint32_t tnxt[PH];
        uint4 qn0, qn1;
        if (p < NPH - 1) {
            const uint32_t* src = Qs + (size_t)(p + 1) * PHW;
            qn0 = *(const uint4*)(src + (size_t)t * 4);
            qn1 = *(const uint4*)(src + (size_t)(t + BT) * 4);
            #pragma unroll
            for (int il = 0; il < PH; ++il)
                tnxt[il] = T[(size_t)((p + 1) * PH + il) * NB + bme];
        }
        #pragma unroll
        for (int il = 0; il < PH; ++il) {
            uint32_t tw  = treg[il];
            uint32_t off = tw & 0xFFFFu;                    // idx*16 bytes
            uint32_t w2b = (tw & 0xFFFF0000u) | 0x3C00u;    // {1.0h, d}
            uint4 q = *(const uint4*)((const char*)&slab[cur][il][0] + off);
            half2v w2 = __builtin_bit_cast(half2v, w2b);
            a0 = __builtin_amdgcn_fdot2(__builtin_bit_cast(half2v, q.x), w2, a0, false);
            a1 = __builtin_amdgcn_fdot2(__builtin_bit_cast(half2v, q.y), w2, a1, false);
            a2 = __builtin_amdgcn_fdot2(__builtin_bit_cast(half2v, q.z), w2, a2, false);
            a3 = __builtin_amdgcn_fdot2(__builtin_bit_cast(half2v, q.w), w2, a3, false);
        }
        if (p < NPH - 1) {
            ((uint4*)&slab[cur ^ 1][0][0])[t]      = qn0;
            ((uint4*)&slab[cur ^ 1][0][0])[t + BT] = qn1;
            #pragma unroll
            for (int il = 0; il < PH; ++il)
                treg[il] = tnxt[il];
            __syncthreads();
        }
    }

    // epilogue: o = s*4 + {0..3}; 512-lane contiguous run per o
    size_t ob = (size_t)(s * 4) * NB + bme;
    __builtin_nontemporal_store(a0, out + ob);
    __builtin_nontemporal_store(a1, out + ob + NB);
    __builtin_nontemporal_store(a2, out + ob + 2 * (size_t)NB);
    __builtin_nontemporal_store(a3, out + ob + 3 * (size_t)NB);
}

extern "C" void kernel_launch(void* const* d_in, const int* in_sizes, int n_in,
                              void* d_out, int out_size, void* d_ws, size_t ws_size,
                              hipStream_t stream) {
    const float* x       = (const float*)d_in[0];
    const float* P       = (const float*)d_in[1];
    const float* borders = (const float*)d_in[2];
    const float* icl     = (const float*)d_in[3];
    float* out = (float*)d_out;

    uint32_t* Q2 = (uint32_t*)d_ws;                 // 8.4 MB
    uint32_t* T  = Q2 + (size_t)NO * NI * NG;       // 4.2 MB

    hipLaunchKernelGGL(build_q, dim3(NG * 4), dim3(256), 0, stream, P, Q2);
    hipLaunchKernelGGL(build_t, dim3(NI * NB / 1024), dim3(256), 0, stream,
                       x, borders, icl, T);
    hipLaunchKernelGGL(main_k, dim3((NB / BT) * 32), dim3(BT), 0, stream,
                       Q2, T, out);
}

// Round 9
// 96.341 us; speedup vs baseline: 1.7488x; 1.7488x over previous
//
#include <hip/hip_runtime.h>
#include <cstdint>

// BasisFunction1D: out[o,b] = sum_i (1-d)*P[idx,o,i] + d*P[idx+1,o,i]
//
// R8 = R7 intent (2 blocks/CU overlap) made spill-proof:
//   - staging via __builtin_amdgcn_global_load_lds (no staging VGPRs)
//   - outer phase loop NOT unrolled (#pragma unroll 1) -> ~40 live VGPRs
//   - R6 lean inner iter: v_and + v_and_or + ds_read_b128 + 4 fdot2
//   Q2[s][i][g][ow]: per-(s,i) slab = 2 KB contiguous. T[i][b]=(idx*16)|(d_h<<16).
//   main: 512 thr = 8 waves = 512 b x 4 o, grid 512 = 2 blocks/CU (64 KB LDS).
//   16 phases x 8 i, double-buffered 2x16 KB; one barrier per phase; the
//   co-resident block covers each barrier's vmcnt drain.

#define NG 128
#define NI 128
#define NO 128
#define NB 8192
#define WO 4
#define PH 8
#define NPH (NI / PH)
#define BT 512
#define PHW (PH * NG * WO)          // u32 per phase slab (4096 = 16 KB)

using half2v = __attribute__((ext_vector_type(2))) _Float16;

__device__ inline uint32_t pack_f16x2(float lo, float hi) {
    _Float16 hl = (_Float16)lo, hh = (_Float16)hi;
    return (uint32_t)__builtin_bit_cast(unsigned short, hl) |
           ((uint32_t)__builtin_bit_cast(unsigned short, hh) << 16);
}

// ---- K1: P[g,o,i] -> Q2[((s*NI+i)*NG+g)*4+ow] = pack(P, dP), o=s*4+ow ----
__global__ __launch_bounds__(256) void build_q(const float* __restrict__ P,
                                               uint32_t* __restrict__ Q2) {
    __shared__ float lp[32][129];
    __shared__ float ln[32][129];
    const int g  = blockIdx.x >> 2;
    const int o0 = (blockIdx.x & 3) * 32;
    const int t  = threadIdx.x;
    #pragma unroll
    for (int p = 0; p < 16; ++p) {
        int e = p * 256 + t;
        int ol = e >> 7, i = e & 127;
        lp[ol][i] = P[(size_t)(g * NO + o0 + ol) * NI + i];
        ln[ol][i] = P[(size_t)((g + 1) * NO + o0 + ol) * NI + i];
    }
    __syncthreads();
    #pragma unroll
    for (int p = 0; p < 4; ++p) {
        int e = p * 256 + t;          // 8 s_loc x 128 i
        int sl = e >> 7, i = e & 127;
        uint32_t r[4];
        #pragma unroll
        for (int ow = 0; ow < 4; ++ow) {
            float pl = lp[sl * 4 + ow][i];
            float dd = ln[sl * 4 + ow][i] - pl;
            r[ow] = pack_f16x2(pl, dd);
        }
        int s = (o0 >> 2) + sl;
        *(uint4*)(Q2 + ((size_t)(s * NI + i) * NG + g) * 4) =
            make_uint4(r[0], r[1], r[2], r[3]);
    }
}

// ---- K2: bucketize x -> T[i][b] = (idx*16) | (f16(d) << 16) ----
__global__ __launch_bounds__(256) void build_t(const float* __restrict__ x,
                                               const float* __restrict__ borders,
                                               const float* __restrict__ icl,
                                               uint32_t* __restrict__ T) {
    const int e0 = (blockIdx.x * 256 + threadIdx.x) * 4;
    const float4 xv = *(const float4*)(x + e0);
    uint32_t r[4];
    const float xs[4] = {xv.x, xv.y, xv.z, xv.w};
    #pragma unroll
    for (int k = 0; k < 4; ++k) {
        float v = xs[k];
        float ea = __expf(-fabsf(v));
        float cdf = v > 0.f ? 1.f - 0.5f * ea : 0.5f * ea;
        int idx = (int)(cdf * 128.f);
        idx = idx > 127 ? 127 : idx;
        float d = (v - borders[idx]) * icl[idx];
        _Float16 hd = (_Float16)d;
        r[k] = ((uint32_t)idx << 4) |
               ((uint32_t)__builtin_bit_cast(unsigned short, hd) << 16);
    }
    *(uint4*)(T + e0) = make_uint4(r[0], r[1], r[2], r[3]);
}

// ---- K3: main. 512 thr; 512 b x 4 o; global_load_lds double-buffer ----
__global__ __launch_bounds__(512) void main_k(const uint32_t* __restrict__ Q2,
                                              const uint32_t* __restrict__ T,
                                              float* __restrict__ out) {
    __shared__ uint32_t slab[2][PH][NG * WO];   // 2 x 16 KB
    const int t    = threadIdx.x;
    const int bx   = blockIdx.x;
    const int s    = bx & 31;                   // o-slice (4 o)
    const int bblk = (bx >> 5) * BT;            // b-tile of 512
    const int bme  = bblk + t;
    const uint32_t* Qs = Q2 + (size_t)s * NI * NG * WO;

    float a0 = 0.f, a1 = 0.f, a2 = 0.f, a3 = 0.f;
    uint32_t treg[PH];

    // prologue: stage phase 0 via direct global->LDS DMA; T phase 0 to regs
    {
        const uint32_t* src = Qs;
        uint32_t* db = &slab[0][0][0];
        __builtin_amdgcn_global_load_lds(
            (const __attribute__((address_space(1))) uint32_t*)(src + (size_t)t * 4),
            (__attribute__((address_space(3))) uint32_t*)(db + (size_t)t * 4),
            16, 0, 0);
        __builtin_amdgcn_global_load_lds(
            (const __attribute__((address_space(1))) uint32_t*)(src + (size_t)(BT + t) * 4),
            (__attribute__((address_space(3))) uint32_t*)(db + (size_t)(BT + t) * 4),
            16, 0, 0);
        #pragma unroll
        for (int il = 0; il < PH; ++il)
            treg[il] = T[(size_t)il * NB + bme];
    }
    __syncthreads();

    #pragma unroll 1
    for (int p = 0; p < NPH; ++p) {
        const uint32_t* sb = &slab[p & 1][0][0];
        uint32_t tnxt[PH];
        if (p < NPH - 1) {
            const uint32_t* src = Qs + (size_t)(p + 1) * PHW;
            uint32_t* db = &slab[(p + 1) & 1][0][0];
            __builtin_amdgcn_global_load_lds(
                (const __attribute__((address_space(1))) uint32_t*)(src + (size_t)t * 4),
                (__attribute__((address_space(3))) uint32_t*)(db + (size_t)t * 4),
                16, 0, 0);
            __builtin_amdgcn_global_load_lds(
                (const __attribute__((address_space(1))) uint32_t*)(src + (size_t)(BT + t) * 4),
                (__attribute__((address_space(3))) uint32_t*)(db + (size_t)(BT + t) * 4),
                16, 0, 0);
            #pragma unroll
            for (int il = 0; il < PH; ++il)
                tnxt[il] = T[(size_t)((p + 1) * PH + il) * NB + bme];
        }
        #pragma unroll
        for (int il = 0; il < PH; ++il) {
            uint32_t tw  = treg[il];
            uint32_t off = tw & 0xFFFFu;                    // idx*16 bytes
            uint32_t w2b = (tw & 0xFFFF0000u) | 0x3C00u;    // {1.0h, d}
            uint4 q = *(const uint4*)((const char*)(sb + il * NG * WO) + off);
            half2v w2 = __builtin_bit_cast(half2v, w2b);
            a0 = __builtin_amdgcn_fdot2(__builtin_bit_cast(half2v, q.x), w2, a0, false);
            a1 = __builtin_amdgcn_fdot2(__builtin_bit_cast(half2v, q.y), w2, a1, false);
            a2 = __builtin_amdgcn_fdot2(__builtin_bit_cast(half2v, q.z), w2, a2, false);
            a3 = __builtin_amdgcn_fdot2(__builtin_bit_cast(half2v, q.w), w2, a3, false);
        }
        if (p < NPH - 1) {
            #pragma unroll
            for (int il = 0; il < PH; ++il)
                treg[il] = tnxt[il];
            __syncthreads();   // drains staging DMA; co-resident block overlaps
        }
    }

    // epilogue: o = s*4 + {0..3}; 512-lane contiguous run per o
    size_t ob = (size_t)(s * 4) * NB + bme;
    __builtin_nontemporal_store(a0, out + ob);
    __builtin_nontemporal_store(a1, out + ob + NB);
    __builtin_nontemporal_store(a2, out + ob + 2 * (size_t)NB);
    __builtin_nontemporal_store(a3, out + ob + 3 * (size_t)NB);
}

extern "C" void kernel_launch(void* const* d_in, const int* in_sizes, int n_in,
                              void* d_out, int out_size, void* d_ws, size_t ws_size,
                              hipStream_t stream) {
    const float* x       = (const float*)d_in[0];
    const float* P       = (const float*)d_in[1];
    const float* borders = (const float*)d_in[2];
    const float* icl     = (const float*)d_in[3];
    float* out = (float*)d_out;

    uint32_t* Q2 = (uint32_t*)d_ws;                 // 8.4 MB
    uint32_t* T  = Q2 + (size_t)NO * NI * NG;       // 4.2 MB

    hipLaunchKernelGGL(build_q, dim3(NG * 4), dim3(256), 0, stream, P, Q2);
    hipLaunchKernelGGL(build_t, dim3(NI * NB / 1024), dim3(256), 0, stream,
                       x, borders, icl, T);
    hipLaunchKernelGGL(main_k, dim3((NB / BT) * 32), dim3(BT), 0, stream,
                       Q2, T, out);
}